// Round 1
// baseline (454.114 us; speedup 1.0000x reference)
//
#include <hip/hip_runtime.h>
#include <hip/hip_bf16.h>

#define B_ 32
#define S_ 2048
#define D_ 1024
#define NCH 16  // sequence chunks for pass1/pass2 partials

// ---------------------------------------------------------------------------
// Probe the mask dtype at runtime (bool may arrive as u8, i32, or f32).
// flag: 1 = int32 {0,1}, 2 = float32 {0.0,1.0}, 0 = byte-sized.
// Reads only the first 1 KB of the mask buffer (safe for all layouts).
__global__ void probe_mask(const unsigned int* __restrict__ m, int* __restrict__ flag) {
    int tid = threadIdx.x;  // 64 threads
    bool isI = true, isF = true;
    for (int i = tid * 4; i < tid * 4 + 4; ++i) {
        unsigned v = m[i];
        if (v > 1u) isI = false;
        if (v != 0u && v != 0x3F800000u) isF = false;
    }
    unsigned long long bi = __ballot(isI);
    unsigned long long bf = __ballot(isF);
    if (tid == 0) {
        int f = 0;
        if (bi == ~0ull) f = 1;
        else if (bf == ~0ull) f = 2;
        *flag = f;
    }
}

// ---------------------------------------------------------------------------
// Pass 1: partial column sums of E over sequence chunks.
// grid (NCH, B), block 256. Each thread owns one float4 of D.
__global__ __launch_bounds__(256) void k1_colsum(const float* __restrict__ E,
                                                 float* __restrict__ part_sums) {
    int chunk = blockIdx.x, b = blockIdx.y, tid = threadIdx.x;
    const float4* base =
        (const float4*)(E + (size_t)(b * S_ + chunk * (S_ / NCH)) * D_);
    float4 acc = make_float4(0.f, 0.f, 0.f, 0.f);
    for (int i = 0; i < S_ / NCH; ++i) {
        float4 e = base[(size_t)i * (D_ / 4) + tid];
        acc.x += e.x; acc.y += e.y; acc.z += e.z; acc.w += e.w;
    }
    ((float4*)part_sums)[(size_t)(b * NCH + chunk) * (D_ / 4) + tid] = acc;
}

// ---------------------------------------------------------------------------
// Reduce partials -> ys (mean over S). 128 blocks x 256.
__global__ void k2a_ys(const float* __restrict__ part_sums, float* __restrict__ ys) {
    int g = blockIdx.x * 256 + threadIdx.x;  // [0, B*D)
    int b = g >> 10, d = g & (D_ - 1);
    float s = 0.f;
    for (int k = 0; k < NCH; ++k) s += part_sums[(size_t)(b * NCH + k) * D_ + d];
    ys[g] = s * (1.0f / S_);
}

// ---------------------------------------------------------------------------
// v[b,d] = sum_e w[d,e] * ys[b,e].  grid (D/256, B), block 256.
__global__ __launch_bounds__(256) void k2b_v(const float* __restrict__ w,
                                             const float* __restrict__ ys,
                                             float* __restrict__ v) {
    int b = blockIdx.y;
    int d = blockIdx.x * 256 + threadIdx.x;
    const float4* wrow = (const float4*)(w + (size_t)d * D_);
    const float4* yb = (const float4*)(ys + (size_t)b * D_);
    float acc = 0.f;
#pragma unroll 4
    for (int e = 0; e < D_ / 4; ++e) {
        float4 wv = wrow[e], yv = yb[e];
        acc += wv.x * yv.x + wv.y * yv.y + wv.z * yv.z + wv.w * yv.w;
    }
    v[(size_t)b * D_ + d] = acc;
}

// ---------------------------------------------------------------------------
// Pass 2 (fused): logits + online softmax partials + weighted-sum partials.
// grid (NCH, B), block 256 (4 waves). Each wave processes 32 full rows:
// lane holds 16 E elements (coalesced float4 x4), dot via wave butterfly,
// online-softmax state (m, l, z[16/lane]) kept in registers.
__global__ __launch_bounds__(256) void k3_fused(
    const float* __restrict__ E, const void* __restrict__ maskp,
    const float* __restrict__ v, const int* __restrict__ flagp,
    float* __restrict__ logits, float* __restrict__ part_m,
    float* __restrict__ part_l, float* __restrict__ part_z) {
    int chunk = blockIdx.x, b = blockIdx.y;
    int tid = threadIdx.x, wave = tid >> 6, lane = tid & 63;
    int mf = *flagp;
    const int* mi = (const int*)maskp;
    const unsigned char* mu = (const unsigned char*)maskp;
    const float* mfl = (const float*)maskp;

    const float4* vf = (const float4*)(v + (size_t)b * D_);
    float4 v0 = vf[lane], v1 = vf[64 + lane], v2 = vf[128 + lane], v3 = vf[192 + lane];

    float m = -3.0e38f, l = 0.0f;
    float4 z0 = make_float4(0.f, 0.f, 0.f, 0.f), z1 = z0, z2 = z0, z3 = z0;

    int sbase = chunk * (S_ / NCH) + wave * 32;
    for (int i = 0; i < 32; ++i) {
        int s = sbase + i;
        const float4* row = (const float4*)(E + (size_t)(b * S_ + s) * D_);
        float4 e0 = row[lane], e1 = row[64 + lane], e2 = row[128 + lane], e3 = row[192 + lane];
        float p = e0.x * v0.x + e0.y * v0.y + e0.z * v0.z + e0.w * v0.w;
        p += e1.x * v1.x + e1.y * v1.y + e1.z * v1.z + e1.w * v1.w;
        p += e2.x * v2.x + e2.y * v2.y + e2.z * v2.z + e2.w * v2.w;
        p += e3.x * v3.x + e3.y * v3.y + e3.z * v3.z + e3.w * v3.w;
#pragma unroll
        for (int off = 32; off; off >>= 1) p += __shfl_xor(p, off, 64);
        int idx = b * S_ + s;
        int mv = (mf == 1) ? (mi[idx] != 0)
                           : (mf == 2 ? (mfl[idx] != 0.0f) : (mu[idx] != 0));
        float logit = mv ? p : -1.0e9f;
        if (lane == 0) logits[idx] = logit;
        if (logit > m) {  // wave-uniform branch (p identical on all lanes)
            float sc = __expf(m - logit);
            l *= sc;
            z0.x *= sc; z0.y *= sc; z0.z *= sc; z0.w *= sc;
            z1.x *= sc; z1.y *= sc; z1.z *= sc; z1.w *= sc;
            z2.x *= sc; z2.y *= sc; z2.z *= sc; z2.w *= sc;
            z3.x *= sc; z3.y *= sc; z3.z *= sc; z3.w *= sc;
            m = logit;
        }
        float pe = __expf(logit - m);
        l += pe;
        z0.x += pe * e0.x; z0.y += pe * e0.y; z0.z += pe * e0.z; z0.w += pe * e0.w;
        z1.x += pe * e1.x; z1.y += pe * e1.y; z1.z += pe * e1.z; z1.w += pe * e1.w;
        z2.x += pe * e2.x; z2.y += pe * e2.y; z2.z += pe * e2.z; z2.w += pe * e2.w;
        z3.x += pe * e3.x; z3.y += pe * e3.y; z3.z += pe * e3.z; z3.w += pe * e3.w;
    }

    // Combine the 4 waves' partials within the block.
    __shared__ float lm[4], ll[4];
    __shared__ float4 zbuf[4][256];  // 16 KiB
    if (lane == 0) { lm[wave] = m; ll[wave] = l; }
    __syncthreads();
    float mb = fmaxf(fmaxf(lm[0], lm[1]), fmaxf(lm[2], lm[3]));
    float lsum = ll[0] * __expf(lm[0] - mb) + ll[1] * __expf(lm[1] - mb) +
                 ll[2] * __expf(lm[2] - mb) + ll[3] * __expf(lm[3] - mb);
    float sc2 = __expf(m - mb);
    zbuf[wave][lane]       = make_float4(z0.x * sc2, z0.y * sc2, z0.z * sc2, z0.w * sc2);
    zbuf[wave][64 + lane]  = make_float4(z1.x * sc2, z1.y * sc2, z1.z * sc2, z1.w * sc2);
    zbuf[wave][128 + lane] = make_float4(z2.x * sc2, z2.y * sc2, z2.z * sc2, z2.w * sc2);
    zbuf[wave][192 + lane] = make_float4(z3.x * sc2, z3.y * sc2, z3.z * sc2, z3.w * sc2);
    __syncthreads();
    float4 a0 = zbuf[0][tid], a1 = zbuf[1][tid], a2 = zbuf[2][tid], a3 = zbuf[3][tid];
    float4 r = make_float4(a0.x + a1.x + a2.x + a3.x, a0.y + a1.y + a2.y + a3.y,
                           a0.z + a1.z + a2.z + a3.z, a0.w + a1.w + a2.w + a3.w);
    ((float4*)(part_z + (size_t)(b * NCH + chunk) * D_))[tid] = r;
    if (tid == 0) { part_m[b * NCH + chunk] = mb; part_l[b * NCH + chunk] = lsum; }
}

// ---------------------------------------------------------------------------
// Merge chunk partials -> zs output + global (m, l) per batch. grid B x 256.
__global__ __launch_bounds__(256) void k4_merge(
    const float* __restrict__ part_m, const float* __restrict__ part_l,
    const float* __restrict__ part_z, float* __restrict__ out_zs,
    float* __restrict__ mg, float* __restrict__ lg) {
    int b = blockIdx.x, tid = threadIdx.x;
    float mb = -3.0e38f;
    for (int i = 0; i < NCH; ++i) mb = fmaxf(mb, part_m[b * NCH + i]);
    float lsum = 0.f;
    for (int i = 0; i < NCH; ++i)
        lsum += part_l[b * NCH + i] * __expf(part_m[b * NCH + i] - mb);
    float4 acc = make_float4(0.f, 0.f, 0.f, 0.f);
    for (int i = 0; i < NCH; ++i) {
        float scl = __expf(part_m[b * NCH + i] - mb);
        float4 zv = ((const float4*)(part_z + (size_t)(b * NCH + i) * D_))[tid];
        acc.x += scl * zv.x; acc.y += scl * zv.y;
        acc.z += scl * zv.z; acc.w += scl * zv.w;
    }
    float inv = 1.0f / lsum;
    ((float4*)(out_zs + (size_t)b * D_))[tid] =
        make_float4(acc.x * inv, acc.y * inv, acc.z * inv, acc.w * inv);
    if (tid == 0) { mg[b] = mb; lg[b] = lsum; }
}

// ---------------------------------------------------------------------------
// f[b,s] = exp(logit - mg[b]) / lg[b].  256 blocks x 256.
__global__ void k5_f(const float* __restrict__ logits, const float* __restrict__ mg,
                     const float* __restrict__ lg, float* __restrict__ out_f) {
    int g = blockIdx.x * 256 + threadIdx.x;
    int b = g >> 11;
    out_f[g] = __expf(logits[g] - mg[b]) * (1.0f / lg[b]);
}

// ---------------------------------------------------------------------------
extern "C" void kernel_launch(void* const* d_in, const int* in_sizes, int n_in,
                              void* d_out, int out_size, void* d_ws, size_t ws_size,
                              hipStream_t stream) {
    const float* E = (const float*)d_in[0];
    const void* maskp = d_in[1];
    const float* w = (const float*)d_in[2];
    float* out = (float*)d_out;  // [B*D] zs, then [B*S] f

    float* ws = (float*)d_ws;
    float* part_sums = ws;                                  // B*NCH*D
    float* ys = part_sums + (size_t)B_ * NCH * D_;          // B*D
    float* v = ys + (size_t)B_ * D_;                        // B*D
    float* logits = v + (size_t)B_ * D_;                    // B*S
    float* part_m = logits + (size_t)B_ * S_;               // B*NCH
    float* part_l = part_m + B_ * NCH;                      // B*NCH
    float* part_z = part_l + B_ * NCH;                      // B*NCH*D
    float* mg = part_z + (size_t)B_ * NCH * D_;             // B
    float* lg = mg + B_;                                    // B
    int* flag = (int*)(lg + B_);                            // 1

    probe_mask<<<1, 64, 0, stream>>>((const unsigned int*)maskp, flag);
    k1_colsum<<<dim3(NCH, B_), 256, 0, stream>>>(E, part_sums);
    k2a_ys<<<(B_ * D_) / 256, 256, 0, stream>>>(part_sums, ys);
    k2b_v<<<dim3(D_ / 256, B_), 256, 0, stream>>>(w, ys, v);
    k3_fused<<<dim3(NCH, B_), 256, 0, stream>>>(E, maskp, v, flag, logits,
                                                part_m, part_l, part_z);
    k4_merge<<<B_, 256, 0, stream>>>(part_m, part_l, part_z, out, mg, lg);
    k5_f<<<(B_ * S_) / 256, 256, 0, stream>>>(logits, mg, lg, out + B_ * D_);
}